// Round 8
// baseline (738.421 us; speedup 1.0000x reference)
//
#include <hip/hip_runtime.h>

#define T_DIM 512
#define L_DIM 128

typedef _Float16 h2 __attribute__((ext_vector_type(2)));

#if defined(__has_builtin)
#if __has_builtin(__builtin_amdgcn_fdot2)
#define HAS_FDOT2 1
#endif
#endif

__device__ __forceinline__ float fdot2_acc(h2 a, h2 b, float c) {
#ifdef HAS_FDOT2
    return __builtin_amdgcn_fdot2(a, b, c, false);
#else
    return c + (float)a.x * (float)b.x + (float)a.y * (float)b.y;
#endif
}

__device__ __forceinline__ unsigned int pack_u32(float a, float b) {
    return __builtin_bit_cast(unsigned int, __builtin_amdgcn_cvt_pkrtz(a, b));
}

#define H2C(x) __builtin_bit_cast(h2, (x))

// LDS-only barrier: drains lgkmcnt but NOT vmcnt, so the global feats
// prefetch stays in flight across the step barrier.
__device__ __forceinline__ void lds_barrier() {
    asm volatile("s_waitcnt lgkmcnt(0)\n\ts_barrier" ::: "memory");
}

// Two waves (128 threads) = TWO independent batch chains (A, B), interleaved
// in one instruction stream. Thread owns output column j = tid for BOTH
// chains; Ehat = exp(transfer)/128 column j (16 named uint4) is SHARED.
//
// Rationale (rounds 0-7): every structure measured ~1250-1500 cy/step with
// VALUBusy ~22-25% -- the step is dominated by the serial LDS round-trip
// (write u -> barrier -> 16 dependent broadcast ds_read_b128 at ~120 cy
// latency -> dot chain), with ~75% of issue slots idle. Chain B's
// independent reads/dots/exps execute inside chain A's latency bubbles:
// 2 chains should cost ~1.1-1.3x one chain's step time.

#define E_GROUPS(X) X(0) X(1) X(2) X(3) X(4) X(5) X(6) X(7) \
                    X(8) X(9) X(10) X(11) X(12) X(13) X(14) X(15)

__global__ __launch_bounds__(128, 1) void crf_fwd_kernel(
    const float* __restrict__ feats,
    const float* __restrict__ transfer,
    const int* __restrict__ target,
    const int* __restrict__ startp,
    const int* __restrict__ stopp,
    float* __restrict__ out)
{
    __shared__ unsigned int LdsUA[2][64] __attribute__((aligned(16)));
    __shared__ unsigned int LdsUB[2][64] __attribute__((aligned(16)));
    __shared__ float LdsRed[16];

    const int tid  = threadIdx.x;       // 0..127
    const int lane = tid & 63;
    const int wv   = tid >> 6;          // 0..1
    const int g    = tid;               // owned output column j (both chains)
    const int b0   = blockIdx.x * 2;
    const int b1   = b0 + 1;
    const int start = startp[0];
    const int stop  = stopp[0];
    const float* fA = feats + (size_t)b0 * T_DIM * L_DIM;
    const float* fB = feats + (size_t)b1 * T_DIM * L_DIM;
    const float LOG128 = 4.852030263919617f;
    const float SCALE  = 0.0078125f;    // 1/128 folded into Ehat

    // ---- Ehat column g: 16 named uint4 (group v = i-rows 8v..8v+7) ----
#define DECL_E(v) uint4 E##v;
    E_GROUPS(DECL_E)
#undef DECL_E

#define LDT(r) transfer[(r) * L_DIM + g]
#define LOAD_E(v) { \
    float e0 = __expf(LDT(8*(v)+0)) * SCALE, e1 = __expf(LDT(8*(v)+1)) * SCALE; \
    float e2 = __expf(LDT(8*(v)+2)) * SCALE, e3 = __expf(LDT(8*(v)+3)) * SCALE; \
    float e4 = __expf(LDT(8*(v)+4)) * SCALE, e5 = __expf(LDT(8*(v)+5)) * SCALE; \
    float e6 = __expf(LDT(8*(v)+6)) * SCALE, e7 = __expf(LDT(8*(v)+7)) * SCALE; \
    E##v.x = pack_u32(e0, e1); E##v.y = pack_u32(e2, e3); \
    E##v.z = pack_u32(e4, e5); E##v.w = pack_u32(e6, e7); }
    E_GROUPS(LOAD_E)
#undef LOAD_E
#undef LDT

    const float trStop = transfer[g * L_DIM + stop];

    // ---- init both chains: u = exp(f_1 + tr[start] + f_2) ----
    {
        float ts0 = transfer[start * L_DIM + g];
        float vA = fA[1 * L_DIM + g] + fA[2 * L_DIM + g] + ts0;
        float vB = fB[1 * L_DIM + g] + fB[2 * L_DIM + g] + ts0;
        _Float16 hA = (_Float16)__expf(vA);
        _Float16 hB = (_Float16)__expf(vB);
        reinterpret_cast<unsigned short*>(&LdsUA[0][0])[g] =
            __builtin_bit_cast(unsigned short, hA);
        reinterpret_cast<unsigned short*>(&LdsUB[0][0])[g] =
            __builtin_bit_cast(unsigned short, hB);
    }
    // feats prefetch rotation, 3 iterations deep, both chains
    float faA = fA[3 * L_DIM + g], faB = fB[3 * L_DIM + g];
    float fbA = fA[4 * L_DIM + g], fbB = fB[4 * L_DIM + g];
    float fcA = fA[5 * L_DIM + g], fcB = fB[5 * L_DIM + g];
    float SA = 0.f, SB = 0.f;
    lds_barrier();

    int cur = 0;
    float accFA = 0.f, accFB = 0.f;

    for (int t = 2; t <= T_DIM - 1; ++t) {
        int tp = t + 4; if (tp > T_DIM - 1) tp = T_DIM - 1;
        float fnA = fA[tp * L_DIM + g];   // in flight across the step
        float fnB = fB[tp * L_DIM + g];
        float eA = __expf(faA);
        float eB = __expf(faB);

        if ((t & 15) == 0) {              // periodic renorm, off-path
            h2 hA = H2C(LdsUA[cur][0]);
            h2 hB = H2C(LdsUB[cur][0]);
            float uA = (float)hA.x, uB = (float)hB.x;
            eA *= 1.0f / uA;  SA += __logf(uA);
            eB *= 1.0f / uB;  SB += __logf(uB);
        }

        const uint4* UA = reinterpret_cast<const uint4*>(&LdsUA[cur][0]);
        const uint4* UB = reinterpret_cast<const uint4*>(&LdsUB[cur][0]);
        float s0 = 0.f, s1 = 0.f, s2 = 0.f, s3 = 0.f;   // chain A
        float q0 = 0.f, q1 = 0.f, q2 = 0.f, q3 = 0.f;   // chain B

        // interleave A and B: B's reads/dots fill A's LDS-latency bubbles
#define DOT_G2(v, AC, BC) { \
        uint4 pa = UA[v]; \
        uint4 pb = UB[v]; \
        AC = fdot2_acc(H2C(pa.x), H2C(E##v.x), AC); \
        AC = fdot2_acc(H2C(pa.y), H2C(E##v.y), AC); \
        AC = fdot2_acc(H2C(pa.z), H2C(E##v.z), AC); \
        AC = fdot2_acc(H2C(pa.w), H2C(E##v.w), AC); \
        BC = fdot2_acc(H2C(pb.x), H2C(E##v.x), BC); \
        BC = fdot2_acc(H2C(pb.y), H2C(E##v.y), BC); \
        BC = fdot2_acc(H2C(pb.z), H2C(E##v.z), BC); \
        BC = fdot2_acc(H2C(pb.w), H2C(E##v.w), BC); }

        DOT_G2(0,  s0, q0) DOT_G2(1,  s1, q1) DOT_G2(2,  s2, q2) DOT_G2(3,  s3, q3)
        DOT_G2(4,  s0, q0) DOT_G2(5,  s1, q1) DOT_G2(6,  s2, q2) DOT_G2(7,  s3, q3)
        DOT_G2(8,  s0, q0) DOT_G2(9,  s1, q1) DOT_G2(10, s2, q2) DOT_G2(11, s3, q3)
        DOT_G2(12, s0, q0) DOT_G2(13, s1, q1) DOT_G2(14, s2, q2) DOT_G2(15, s3, q3)
#undef DOT_G2

        float accA = (s0 + s1) + (s2 + s3);
        float accB = (q0 + q1) + (q2 + q3);

        if (t < T_DIM - 1) {
            _Float16 hA = (_Float16)(accA * eA);
            _Float16 hB = (_Float16)(accB * eB);
            reinterpret_cast<unsigned short*>(&LdsUA[cur ^ 1][0])[g] =
                __builtin_bit_cast(unsigned short, hA);
            reinterpret_cast<unsigned short*>(&LdsUB[cur ^ 1][0])[g] =
                __builtin_bit_cast(unsigned short, hB);
            lds_barrier();                // 2-wave rendezvous, lgkm only
            cur ^= 1;
            faA = fbA; fbA = fcA; fcA = fnA;
            faB = fbB; fbB = fcB; fcB = fnB;
        } else {
            accFA = accA; accFB = accB;
        }
    }

    // 510 dots, each carrying the folded 1/128
    SA += 510.0f * LOG128;
    SB += 510.0f * LOG128;

    // ---- sentence = LSE_j(log u_j + S + tr[j,stop]) over 128 threads ----
    float xA = __logf(accFA) + SA + trStop;
    float xB = __logf(accFB) + SB + trStop;
    float mA = xA, mB = xB;
#pragma unroll
    for (int d = 1; d < 64; d <<= 1) {
        mA = fmaxf(mA, __shfl_xor(mA, d));
        mB = fmaxf(mB, __shfl_xor(mB, d));
    }
    float eAx = __expf(xA - mA), eBx = __expf(xB - mB);
#pragma unroll
    for (int d = 1; d < 64; d <<= 1) {
        eAx += __shfl_xor(eAx, d);
        eBx += __shfl_xor(eBx, d);
    }
    if (lane == 0) {
        LdsRed[0 + wv] = mA;  LdsRed[2 + wv] = eAx;
        LdsRed[8 + wv] = mB;  LdsRed[10 + wv] = eBx;
    }

    // ---- gold scores: 4 t's per thread per chain ----
    float esA = 0.f, tsA = 0.f, esB = 0.f, tsB = 0.f;
    const int* tgA = target + b0 * T_DIM;
    const int* tgB = target + b1 * T_DIM;
#pragma unroll
    for (int k = 0; k < 4; ++k) {
        int t = 1 + tid + (k << 7);
        if (t < T_DIM) {
            int a = tgA[t], bb = tgB[t];
            esA += fA[t * L_DIM + a];
            esB += fB[t * L_DIM + bb];
            int pa = (t == 1) ? start : tgA[t - 1];
            int pb = (t == 1) ? start : tgB[t - 1];
            tsA += transfer[pa * L_DIM + a];
            tsB += transfer[pb * L_DIM + bb];
        }
    }
#pragma unroll
    for (int d = 1; d < 64; d <<= 1) {
        esA += __shfl_xor(esA, d);  tsA += __shfl_xor(tsA, d);
        esB += __shfl_xor(esB, d);  tsB += __shfl_xor(tsB, d);
    }
    if (lane == 0) {
        LdsRed[4 + wv]  = esA; LdsRed[6 + wv]  = tsA;
        LdsRed[12 + wv] = esB; LdsRed[14 + wv] = tsB;
    }
    __syncthreads();

    if (tid == 0) {
        float MA = fmaxf(LdsRed[0], LdsRed[1]);
        float SsA = LdsRed[2] * __expf(LdsRed[0] - MA)
                  + LdsRed[3] * __expf(LdsRed[1] - MA);
        float sentA = MA + __logf(SsA);
        float emA = LdsRed[4] + LdsRed[5];
        float tnA = LdsRed[6] + LdsRed[7];
        out[b0] = sentA - __expf(fA[start] + emA + tnA);

        float MB = fmaxf(LdsRed[8], LdsRed[9]);
        float SsB = LdsRed[10] * __expf(LdsRed[8] - MB)
                  + LdsRed[11] * __expf(LdsRed[9] - MB);
        float sentB = MB + __logf(SsB);
        float emB = LdsRed[12] + LdsRed[13];
        float tnB = LdsRed[14] + LdsRed[15];
        out[b1] = sentB - __expf(fB[start] + emB + tnB);
    }
}

extern "C" void kernel_launch(void* const* d_in, const int* in_sizes, int n_in,
                              void* d_out, int out_size, void* d_ws, size_t ws_size,
                              hipStream_t stream) {
    const float* feats    = (const float*)d_in[0];
    const float* transfer = (const float*)d_in[1];
    const int*   target   = (const int*)d_in[2];
    const int*   startp   = (const int*)d_in[3];
    const int*   stopp    = (const int*)d_in[4];
    float* outp = (float*)d_out;
    int B = in_sizes[0] / (T_DIM * L_DIM);
    hipLaunchKernelGGL(crf_fwd_kernel, dim3(B / 2), dim3(128), 0, stream,
                       feats, transfer, target, startp, stopp, outp);
}

// Round 9
// 419.072 us; speedup vs baseline: 1.7620x; 1.7620x over previous
//
#include <hip/hip_runtime.h>

#define T_DIM 512
#define L_DIM 128

typedef _Float16 h2 __attribute__((ext_vector_type(2)));

#if defined(__has_builtin)
#if __has_builtin(__builtin_amdgcn_fdot2)
#define HAS_FDOT2 1
#endif
#endif

__device__ __forceinline__ float fdot2_acc(h2 a, h2 b, float c) {
#ifdef HAS_FDOT2
    return __builtin_amdgcn_fdot2(a, b, c, false);
#else
    return c + (float)a.x * (float)b.x + (float)a.y * (float)b.y;
#endif
}

__device__ __forceinline__ unsigned int pack_u32(float a, float b) {
    return __builtin_bit_cast(unsigned int, __builtin_amdgcn_cvt_pkrtz(a, b));
}

#define H2C(x) __builtin_bit_cast(h2, (x))

// LDS-only barrier: drains lgkmcnt but NOT vmcnt, so the global feats
// prefetch stays in flight across the step barrier.
__device__ __forceinline__ void lds_barrier() {
    asm volatile("s_waitcnt lgkmcnt(0)\n\ts_barrier" ::: "memory");
}

// Two waves (128 threads) = one batch chain; thread owns output column
// j = tid. Ehat = exp(transfer)/128 column j: 16 named uint4.
//
// ROUND-9 CHANGE (one change vs the round-4 296us kernel): all 16
// broadcast ds_read_b128 of the state u are issued as a SINGLE BLOCK of
// named locals, fenced by sched_barrier(0) before the dot chains.
// Evidence from rounds 2-8: step time ~= (#ds_read_b128) x ~87cy across
// every structure (16 reads -> 1365-1393 cy; 17 -> ~1500; 32 -> 2886),
// i.e. the pressure-minimizing scheduler serializes read->use pairs and
// exposes each read's full LDS latency. Batching the independent reads
// pays ONE latency instead of sixteen.

#define E_GROUPS(X) X(0) X(1) X(2) X(3) X(4) X(5) X(6) X(7) \
                    X(8) X(9) X(10) X(11) X(12) X(13) X(14) X(15)

__global__ __launch_bounds__(128, 1) void crf_fwd_kernel(
    const float* __restrict__ feats,
    const float* __restrict__ transfer,
    const int* __restrict__ target,
    const int* __restrict__ startp,
    const int* __restrict__ stopp,
    float* __restrict__ out)
{
    __shared__ unsigned int LdsU[2][64] __attribute__((aligned(16)));
    __shared__ float LdsRed[8];

    const int tid  = threadIdx.x;       // 0..127
    const int lane = tid & 63;
    const int wv   = tid >> 6;          // 0..1
    const int g    = tid;               // owned output column j
    const int b    = blockIdx.x;
    const int start = startp[0];
    const int stop  = stopp[0];
    const float* fbase = feats + (size_t)b * T_DIM * L_DIM;
    const float LOG128 = 4.852030263919617f;
    const float SCALE  = 0.0078125f;    // 1/128 folded into Ehat

    // ---- Ehat column g: 16 named uint4 (group v = i-rows 8v..8v+7) ----
#define DECL_E(v) uint4 E##v;
    E_GROUPS(DECL_E)
#undef DECL_E

#define LDT(r) transfer[(r) * L_DIM + g]
#define LOAD_E(v) { \
    float e0 = __expf(LDT(8*(v)+0)) * SCALE, e1 = __expf(LDT(8*(v)+1)) * SCALE; \
    float e2 = __expf(LDT(8*(v)+2)) * SCALE, e3 = __expf(LDT(8*(v)+3)) * SCALE; \
    float e4 = __expf(LDT(8*(v)+4)) * SCALE, e5 = __expf(LDT(8*(v)+5)) * SCALE; \
    float e6 = __expf(LDT(8*(v)+6)) * SCALE, e7 = __expf(LDT(8*(v)+7)) * SCALE; \
    E##v.x = pack_u32(e0, e1); E##v.y = pack_u32(e2, e3); \
    E##v.z = pack_u32(e4, e5); E##v.w = pack_u32(e6, e7); }
    E_GROUPS(LOAD_E)
#undef LOAD_E
#undef LDT

    const float trStop = transfer[g * L_DIM + stop];

    // ---- init: u = exp(f_1 + tr[start] + f_2) ----
    {
        float v2 = fbase[1 * L_DIM + g] + fbase[2 * L_DIM + g]
                 + transfer[start * L_DIM + g];
        _Float16 h = (_Float16)__expf(v2);
        reinterpret_cast<unsigned short*>(&LdsU[0][0])[g] =
            __builtin_bit_cast(unsigned short, h);
    }
    // feats prefetch pipeline, 3 iterations deep
    float fa = fbase[3 * L_DIM + g];    // f_{t+1} consumed at t=2
    float fb = fbase[4 * L_DIM + g];
    float fc = fbase[5 * L_DIM + g];
    float S  = 0.f;
    lds_barrier();

    int cur = 0;
    float accF = 0.f;

    for (int t = 2; t <= T_DIM - 1; ++t) {
        int tp = t + 4; if (tp > T_DIM - 1) tp = T_DIM - 1;
        float fnew = fbase[tp * L_DIM + g];   // in flight (vmcnt)
        float e = __expf(fa);

        if ((t & 15) == 0) {                  // periodic renorm, off-path
            h2 h = H2C(LdsU[cur][0]);
            float u0 = (float)h.x;
            e *= 1.0f / u0;
            S += __logf(u0);
        }

        const uint4* U4p = reinterpret_cast<const uint4*>(&LdsU[cur][0]);

        // ---- batch ALL 16 broadcast reads, then fence ----
        uint4 p0  = U4p[0],  p1  = U4p[1],  p2  = U4p[2],  p3  = U4p[3];
        uint4 p4  = U4p[4],  p5  = U4p[5],  p6  = U4p[6],  p7  = U4p[7];
        uint4 p8  = U4p[8],  p9  = U4p[9],  p10 = U4p[10], p11 = U4p[11];
        uint4 p12 = U4p[12], p13 = U4p[13], p14 = U4p[14], p15 = U4p[15];
        __builtin_amdgcn_sched_barrier(0);    // reads stay batched above

        float s0 = 0.f, s1 = 0.f, s2 = 0.f, s3 = 0.f;

#define DOT_G(v, AC) { \
        AC = fdot2_acc(H2C(p##v.x), H2C(E##v.x), AC); \
        AC = fdot2_acc(H2C(p##v.y), H2C(E##v.y), AC); \
        AC = fdot2_acc(H2C(p##v.z), H2C(E##v.z), AC); \
        AC = fdot2_acc(H2C(p##v.w), H2C(E##v.w), AC); }

        DOT_G(0,  s0) DOT_G(1,  s1) DOT_G(2,  s2) DOT_G(3,  s3)
        DOT_G(4,  s0) DOT_G(5,  s1) DOT_G(6,  s2) DOT_G(7,  s3)
        DOT_G(8,  s0) DOT_G(9,  s1) DOT_G(10, s2) DOT_G(11, s3)
        DOT_G(12, s0) DOT_G(13, s1) DOT_G(14, s2) DOT_G(15, s3)
#undef DOT_G

        float acc = (s0 + s1) + (s2 + s3);

        if (t < T_DIM - 1) {
            _Float16 h = (_Float16)(acc * e);
            reinterpret_cast<unsigned short*>(&LdsU[cur ^ 1][0])[g] =
                __builtin_bit_cast(unsigned short, h);
            lds_barrier();                    // 2-wave rendezvous, lgkm only
            cur ^= 1;
            fa = fb; fb = fc; fc = fnew;
        } else {
            accF = acc;
        }
    }

    // 510 dots, each carrying the folded 1/128
    S += 510.0f * LOG128;

    // ---- sentence = LSE_j(log u_j + S + tr[j,stop]) over 128 lanes ----
    float x  = __logf(accF) + S + trStop;
    float mx = x;
#pragma unroll
    for (int d = 1; d < 64; d <<= 1) mx = fmaxf(mx, __shfl_xor(mx, d));
    float ex = __expf(x - mx);
#pragma unroll
    for (int d = 1; d < 64; d <<= 1) ex += __shfl_xor(ex, d);
    if (lane == 0) { LdsRed[wv] = mx; LdsRed[2 + wv] = ex; }

    // ---- gold score: 4 t's per thread, coalesced target loads ----
    float es = 0.f, ts = 0.f;
    const int* tgt = target + b * T_DIM;
#pragma unroll
    for (int k = 0; k < 4; ++k) {
        int t = 1 + tid + (k << 7);
        if (t < T_DIM) {
            int tg = tgt[t];
            es += fbase[t * L_DIM + tg];
            int pr = (t == 1) ? start : tgt[t - 1];
            ts += transfer[pr * L_DIM + tg];
        }
    }
#pragma unroll
    for (int d = 1; d < 64; d <<= 1) {
        es += __shfl_xor(es, d);
        ts += __shfl_xor(ts, d);
    }
    if (lane == 0) { LdsRed[4 + wv] = es; LdsRed[6 + wv] = ts; }
    __syncthreads();

    if (tid == 0) {
        float M  = fmaxf(LdsRed[0], LdsRed[1]);
        float Ss = LdsRed[2] * __expf(LdsRed[0] - M)
                 + LdsRed[3] * __expf(LdsRed[1] - M);
        float sentence = M + __logf(Ss);
        float em = LdsRed[4] + LdsRed[5];
        float tn = LdsRed[6] + LdsRed[7];
        float emit0 = fbase[start];           // feats[b, 0, start]
        out[b] = sentence - __expf(emit0 + em + tn);
    }
}

extern "C" void kernel_launch(void* const* d_in, const int* in_sizes, int n_in,
                              void* d_out, int out_size, void* d_ws, size_t ws_size,
                              hipStream_t stream) {
    const float* feats    = (const float*)d_in[0];
    const float* transfer = (const float*)d_in[1];
    const int*   target   = (const int*)d_in[2];
    const int*   startp   = (const int*)d_in[3];
    const int*   stopp    = (const int*)d_in[4];
    float* outp = (float*)d_out;
    int B = in_sizes[0] / (T_DIM * L_DIM);
    hipLaunchKernelGGL(crf_fwd_kernel, dim3(B), dim3(128), 0, stream,
                       feats, transfer, target, startp, stopp, outp);
}